// Round 4
// baseline (14022.455 us; speedup 1.0000x reference)
//
#include <hip/hip_runtime.h>
#include <stdint.h>

#define NB 1024
#define NT 100
#define NPRED 30
#define NE 512
#define NH 1024
#define NG (3*NH)

typedef unsigned short u16;
typedef unsigned int u32;
typedef u16 u16x4 __attribute__((ext_vector_type(4)));
typedef float f32x4 __attribute__((ext_vector_type(4)));
typedef __bf16 bf16x8 __attribute__((ext_vector_type(8)));

__device__ __forceinline__ u16 f2b(float f){
  u32 u = __float_as_uint(f);
  u = (u + 0x7FFFu + ((u >> 16) & 1u)) >> 16;
  return (u16)u;
}
__device__ __forceinline__ float sig_(float x){ return 1.0f/(1.0f+__expf(-x)); }
__device__ __forceinline__ float tanh_(float x){
  float e = __expf(2.0f*fabsf(x));
  return copysignf(1.0f - 2.0f/(e+1.0f), x);
}

// ---------------- fp32 -> bf16 conversion ----------------
__global__ void cvt_kernel(const float* src, u16* dst, int n4){
  int i = blockIdx.x*256 + threadIdx.x;
  if (i < n4){
    f32x4 v = ((const f32x4*)src)[i];
    u16x4 o;
    o[0]=f2b(v[0]); o[1]=f2b(v[1]); o[2]=f2b(v[2]); o[3]=f2b(v[3]);
    ((u16x4*)dst)[i] = o;
  }
}

// ---------------- bulk input embedding for steps [t0, t0+Ce) ----------------
__global__ void embN_kernel(const float* __restrict__ obs, const float* __restrict__ We,
                            const float* __restrict__ be, u16* __restrict__ out, int t0){
  int idx = blockIdx.x*256 + threadIdx.x;
  int e = idx & 511, rb = idx >> 9;
  int tc = rb >> 10, b = rb & 1023;
  float x0 = obs[(b*NT + t0 + tc)*2], x1 = obs[(b*NT + t0 + tc)*2 + 1];
  out[idx] = f2b(tanh_(We[e*2]*x0 + We[e*2+1]*x1 + be[e]));
}

__global__ void emb_kernel(const float* __restrict__ obs, const float* __restrict__ We,
                           const float* __restrict__ be, u16* __restrict__ out, int t){
  int idx = blockIdx.x*256 + threadIdx.x;
  int b = idx >> 9, e = idx & 511;
  float x0 = obs[(b*NT + t)*2], x1 = obs[(b*NT + t)*2 + 1];
  out[idx] = f2b(tanh_(We[e*2]*x0 + We[e*2+1]*x1 + be[e]));
}

__global__ void demb_kernel(const float* __restrict__ last, const float* __restrict__ Wed,
                            const float* __restrict__ bed, u16* __restrict__ out){
  int idx = blockIdx.x*256 + threadIdx.x;
  int b = idx >> 9, e = idx & 511;
  out[idx] = f2b(tanh_(Wed[e*2]*last[b*2] + Wed[e*2+1]*last[b*2+1] + bed[e]));
}

// ---------------- async global->LDS (16B per lane) ----------------
__device__ __forceinline__ void gload16(const u16* g, const u16* lds){
  __builtin_amdgcn_global_load_lds(
      (const __attribute__((address_space(1))) void*)g,
      (__attribute__((address_space(3))) void*)lds, 16, 0, 0);
}

// ---------------- bulk 128x128 GEMM (m97-lite) for gx precompute ----------------
__global__ __launch_bounds__(256)
void gemm_big_kernel(const u16* A, int K, const u16* W,
                     const float* bias, float* C)
{
  __shared__ __align__(16) u16 As[128][32];
  __shared__ __align__(16) u16 Bs[128][32];

  const int bRow = blockIdx.y * 128;
  const int bCol = blockIdx.x * 128;
  const int tid = threadIdx.x;
  const int w = tid >> 6, l = tid & 63;
  const int wm = w >> 1, wn = w & 1;
  const int lrow = l >> 2, lcol = (l & 3) * 8;
  const int fr = l & 15, fk = (l >> 4) * 8;

  f32x4 acc[4][4];
  #pragma unroll
  for (int m=0;m<4;m++)
    #pragma unroll
    for (int n=0;n<4;n++) acc[m][n] = (f32x4)0.0f;

  const u16* Ab = A + (size_t)(bRow + lrow)*K + lcol;
  const u16* Wb = W + (size_t)(bCol + lrow)*K + lcol;

  for (int k0 = 0; k0 < K; k0 += 32){
    #pragma unroll
    for (int c=0;c<2;c++){
      int r0 = w*32 + c*16;
      gload16(Ab + (size_t)r0*K + k0, &As[r0][0]);
      gload16(Wb + (size_t)r0*K + k0, &Bs[r0][0]);
    }
    __syncthreads();

    bf16x8 af[4], bfr[4];
    #pragma unroll
    for (int m=0;m<4;m++) af[m]  = *(const bf16x8*)&As[wm*64 + m*16 + fr][fk];
    #pragma unroll
    for (int n=0;n<4;n++) bfr[n] = *(const bf16x8*)&Bs[wn*64 + n*16 + fr][fk];

    #pragma unroll
    for (int m=0;m<4;m++)
      #pragma unroll
      for (int n=0;n<4;n++)
        acc[m][n] = __builtin_amdgcn_mfma_f32_16x16x32_bf16(af[m], bfr[n], acc[m][n], 0, 0, 0);

    __syncthreads();
  }

  const int crow = (l >> 4) * 4, ccol = l & 15;
  #pragma unroll
  for (int n=0;n<4;n++){
    int col = bCol + wn*64 + n*16 + ccol;
    float bv = bias[col];
    #pragma unroll
    for (int m=0;m<4;m++){
      int row = bRow + wm*64 + m*16 + crow;
      float* Cp = C + (size_t)row*NG + col;
      #pragma unroll
      for (int r=0;r<4;r++) Cp[(size_t)r*NG] = acc[m][n][r] + bv;
    }
  }
}

// ---------------- fused GRU step ----------------
// Block: 64 rows x 64 h-cols; computes all 3 gate columns (W-tile 192 rows),
// optional inline gx pass, then GRU cell in epilogue. Grid (16,16), 256 thr.
// Double-buffered LDS, single __syncthreads per k-iter (stage t+1 -> compute t -> sync).
__device__ __forceinline__ void gemm_pass(
    const u16* __restrict__ A, const u16* __restrict__ W, int K,
    int bRow, int bCol, int w, int l,
    u16 (*As)[64][32], u16 (*Ws)[192][32],
    f32x4* acc, f32x4* accx, bool xside)
{
  const int lrow = l >> 2, lcol = (l & 3) * 8;
  const int fr = l & 15, fk = (l >> 4) * 8;
  const u16* Ab = A + (size_t)(bRow + lrow)*K + lcol;
  const u16* Wb = W + (size_t)(bCol + lrow)*K + lcol;
  const int NK = K >> 5;

  // stage(t, buf)
  {
    gload16(Ab + (size_t)(w*16)*K, &As[0][w*16][0]);
    #pragma unroll
    for (int c=0;c<3;c++){
      int s = w + c*4;
      gload16(Wb + ((size_t)(s>>2)*NH + (s&3)*16)*K, &Ws[0][s*16][0]);
    }
  }
  __syncthreads();

  for (int t = 0; t < NK; ++t){
    int cur = t & 1;
    if (t + 1 < NK){
      int k0 = (t+1)*32, nb = cur^1;
      gload16(Ab + (size_t)(w*16)*K + k0, &As[nb][w*16][0]);
      #pragma unroll
      for (int c=0;c<3;c++){
        int s = w + c*4;
        gload16(Wb + ((size_t)(s>>2)*NH + (s&3)*16)*K + k0, &Ws[nb][s*16][0]);
      }
    }
    bf16x8 af = *(const bf16x8*)&As[cur][w*16 + fr][fk];
    #pragma unroll
    for (int g=0;g<3;g++)
      #pragma unroll
      for (int n=0;n<4;n++){
        bf16x8 bf = *(const bf16x8*)&Ws[cur][g*64 + n*16 + fr][fk];
        if (xside && g == 2)
          accx[n] = __builtin_amdgcn_mfma_f32_16x16x32_bf16(af, bf, accx[n], 0, 0, 0);
        else
          acc[g*4+n] = __builtin_amdgcn_mfma_f32_16x16x32_bf16(af, bf, acc[g*4+n], 0, 0, 0);
      }
    __syncthreads();
  }
}

__global__ __launch_bounds__(256)
void fused_gru_step(
    const float* __restrict__ gxp,                    // non-null: precomputed gx (incl. bih)
    const u16* __restrict__ Ax, int Kx,
    const u16* __restrict__ Wih, const float* __restrict__ bih,   // inline-gx pass
    const u16* __restrict__ Ah, const u16* __restrict__ Whh, const float* __restrict__ bhh,
    const float* __restrict__ hin, float* __restrict__ houtf,
    u16* __restrict__ houtb, u16* __restrict__ seq)
{
  __shared__ __align__(16) u16 As[2][64][32];
  __shared__ __align__(16) u16 Ws[2][192][32];

  const int tid = threadIdx.x;
  const int w = tid >> 6, l = tid & 63;
  const int bRow = blockIdx.y * 64;
  const int bCol = blockIdx.x * 64;

  f32x4 acc[12], accx[4];
  #pragma unroll
  for (int i=0;i<12;i++) acc[i] = (f32x4)0.0f;
  #pragma unroll
  for (int i=0;i<4;i++) accx[i] = (f32x4)0.0f;

  if (!gxp)
    gemm_pass(Ax, Wih, Kx, bRow, bCol, w, l, As, Ws, acc, accx, true);
  gemm_pass(Ah, Whh, NH, bRow, bCol, w, l, As, Ws, acc, accx, false);

  // epilogue: GRU cell. C/D layout: col = lane&15, row = (lane>>4)*4 + reg
  #pragma unroll
  for (int n=0;n<4;n++){
    int j = bCol + n*16 + (l & 15);
    float bhr = bhh[j], bhz = bhh[NH + j], bhn = bhh[2*NH + j];
    float bxr = 0.f, bxz = 0.f, bxn = 0.f;
    if (!gxp){ bxr = bih[j]; bxz = bih[NH + j]; bxn = bih[2*NH + j]; }
    #pragma unroll
    for (int r=0;r<4;r++){
      int row = bRow + w*16 + (l >> 4)*4 + r;
      size_t hoff = (size_t)row*NH + j;
      float rpre, zpre, nx, nh;
      if (gxp){
        size_t goff = (size_t)row*NG + j;
        rpre = gxp[goff]        + acc[n][r]   + bhr;
        zpre = gxp[goff + NH]   + acc[4+n][r] + bhz;
        nx   = gxp[goff + 2*NH];
        nh   = acc[8+n][r] + bhn;
      } else {
        rpre = acc[n][r]   + bxr + bhr;
        zpre = acc[4+n][r] + bxz + bhz;
        nx   = accx[n][r]  + bxn;
        nh   = acc[8+n][r] + bhn;
      }
      float r_ = sig_(rpre), z_ = sig_(zpre);
      float nn = tanh_(nx + r_*nh);
      float h = (1.0f - z_)*nn + z_*hin[hoff];
      houtf[hoff] = h;
      u16 hb16 = f2b(h);
      houtb[hoff] = hb16;
      if (seq) seq[hoff] = hb16;
    }
  }
}

// ---------------- output projection: (B,H) @ Wout^T (2,H) + bout ----------------
__global__ void outproj_kernel(const float* __restrict__ h, const float* __restrict__ Wout,
                               const float* __restrict__ bout, float* __restrict__ last,
                               float* __restrict__ dout, int t)
{
  int b = blockIdx.x, tid = threadIdx.x;
  float s0 = 0.f, s1 = 0.f;
  const float* hb_ = h + (size_t)b*NH;
  for (int j = tid; j < NH; j += 256){
    float hv = hb_[j];
    s0 += hv * Wout[j];
    s1 += hv * Wout[NH + j];
  }
  #pragma unroll
  for (int off = 32; off > 0; off >>= 1){
    s0 += __shfl_down(s0, off);
    s1 += __shfl_down(s1, off);
  }
  __shared__ float red[8];
  int w = tid >> 6;
  if ((tid & 63) == 0){ red[w*2] = s0; red[w*2+1] = s1; }
  __syncthreads();
  if (tid == 0){
    float o0 = red[0]+red[2]+red[4]+red[6] + bout[0];
    float o1 = red[1]+red[3]+red[5]+red[7] + bout[1];
    last[b*2]   = o0;
    last[b*2+1] = o1;
    if (dout){ dout[(size_t)b*(NPRED*2) + t*2]     = o0;
               dout[(size_t)b*(NPRED*2) + t*2 + 1] = o1; }
  }
}

extern "C" void kernel_launch(void* const* d_in, const int* in_sizes, int n_in,
                              void* d_out, int out_size, void* d_ws, size_t ws_size,
                              hipStream_t stream)
{
  (void)in_sizes; (void)n_in; (void)out_size;
  const float* obs  = (const float*)d_in[0];
  const float* We   = (const float*)d_in[1];
  const float* be   = (const float*)d_in[2];
  const float* Wed  = (const float*)d_in[3];
  const float* bed  = (const float*)d_in[4];
  const float* e1Wih = (const float*)d_in[5];
  const float* e1Whh = (const float*)d_in[6];
  const float* e1bih = (const float*)d_in[7];
  const float* e1bhh = (const float*)d_in[8];
  const float* e2Wih = (const float*)d_in[9];
  const float* e2Whh = (const float*)d_in[10];
  const float* e2bih = (const float*)d_in[11];
  const float* e2bhh = (const float*)d_in[12];
  const float* d1Wih = (const float*)d_in[13];
  const float* d1Whh = (const float*)d_in[14];
  const float* d1bih = (const float*)d_in[15];
  const float* d1bhh = (const float*)d_in[16];
  const float* d2Wih = (const float*)d_in[17];
  const float* d2Whh = (const float*)d_in[18];
  const float* d2bih = (const float*)d_in[19];
  const float* d2bhh = (const float*)d_in[20];
  const float* Wout = (const float*)d_in[21];
  const float* bout = (const float*)d_in[22];
  float* out = (float*)d_out;

  // ---- workspace ----
  char* ws = (char*)d_ws;
  size_t off = 0;
  auto alloc = [&](size_t bytes)->char* {
    char* p = ws + off;
    off += (bytes + 255) & ~(size_t)255;
    return p;
  };
  u16* wE1i = (u16*)alloc((size_t)NG*NE*2);
  u16* wE1h = (u16*)alloc((size_t)NG*NH*2);
  u16* wE2i = (u16*)alloc((size_t)NG*NH*2);
  u16* wE2h = (u16*)alloc((size_t)NG*NH*2);
  u16* wD1i = (u16*)alloc((size_t)NG*NE*2);
  u16* wD1h = (u16*)alloc((size_t)NG*NH*2);
  u16* wD2i = (u16*)alloc((size_t)NG*NH*2);
  u16* wD2h = (u16*)alloc((size_t)NG*NH*2);
  u16* embb  = (u16*)alloc((size_t)NB*NE*2);
  float* h1f = (float*)alloc((size_t)NB*NH*4);
  u16*   h1b2[2] = { (u16*)alloc((size_t)NB*NH*2), (u16*)alloc((size_t)NB*NH*2) };
  float* h2f = (float*)alloc((size_t)NB*NH*4);
  u16*   h2b2[2] = { (u16*)alloc((size_t)NB*NH*2), (u16*)alloc((size_t)NB*NH*2) };
  float* last = (float*)alloc((size_t)NB*2*4);

  // ws-adaptive: enc1 cache (priority), then gx chunk size C
  const size_t slot = (size_t)NB*NH*2;                               // 2 MB/step
  const size_t chunk_unit = (size_t)NB*NE*2 + (size_t)NB*NG*4 + 512; // ~13.6 MB
  size_t rem = (ws_size > off) ? ws_size - off : 0;
  int cs = 0, C = 1;
  if (rem > chunk_unit + (1u<<20)){
    size_t rem2 = rem - chunk_unit - (1u<<20);
    cs = (int)(rem2 / slot); if (cs > NT) cs = NT;
    rem2 -= (size_t)cs * slot;
    C = 1 + (int)(rem2 / chunk_unit);
    if (C > 25) C = 25; if (C > NT) C = NT;
  }
  u16* cache = (u16*)alloc((size_t)cs * slot);
  u16* embc  = (u16*)alloc((size_t)C*NB*NE*2);
  float* gxbuf = (float*)alloc((size_t)C*NB*NG*4);
  const int cache_start = NT - cs;

  // ---- init ----
  hipMemsetAsync(h1f, 0, (size_t)NB*NH*4, stream);
  hipMemsetAsync(h1b2[0], 0, (size_t)NB*NH*2, stream);

  auto cvt = [&](const float* src, u16* dst, size_t n){
    int n4 = (int)(n >> 2);
    cvt_kernel<<<dim3((n4 + 255)/256), dim3(256), 0, stream>>>(src, dst, n4);
  };
  cvt(e1Wih, wE1i, (size_t)NG*NE);
  cvt(e1Whh, wE1h, (size_t)NG*NH);
  cvt(e2Wih, wE2i, (size_t)NG*NH);
  cvt(e2Whh, wE2h, (size_t)NG*NH);
  cvt(d1Wih, wD1i, (size_t)NG*NE);
  cvt(d1Whh, wD1h, (size_t)NG*NH);
  cvt(d2Wih, wD2i, (size_t)NG*NH);
  cvt(d2Whh, wD2h, (size_t)NG*NH);

  const dim3 blk(256);
  const dim3 fgrid(16, 16);          // 256 blocks, 64x64 h-tiles
  const dim3 emb_grid((NB*NE)/256);

  int p1 = 0, p2 = 0;

  // ---- pass 1: GRU1 (gx bulk-hoisted; fused gh+cell per step) ----
  for (int t0 = 0; t0 < NT; t0 += C){
    int Ce = (NT - t0 < C) ? NT - t0 : C;
    embN_kernel<<<dim3(Ce*2048), blk, 0, stream>>>(obs, We, be, embc, t0);
    gemm_big_kernel<<<dim3(NG/128, Ce*8), blk, 0, stream>>>(embc, NE, wE1i, e1bih, gxbuf);
    for (int tc = 0; tc < Ce; ++tc){
      int t = t0 + tc;
      u16* slot_p = (t >= cache_start) ? cache + (size_t)(t - cache_start)*NB*NH : (u16*)nullptr;
      fused_gru_step<<<fgrid, blk, 0, stream>>>(
          gxbuf + (size_t)tc*NB*NG, nullptr, 0, nullptr, nullptr,
          h1b2[p1], wE1h, e1bhh, h1f, h1f, h1b2[p1^1], slot_p);
      p1 ^= 1;
    }
  }

  // GRU2 h0 = GRU1 final h (the reference quirk)
  hipMemcpyAsync(h2f, h1f, (size_t)NB*NH*4, hipMemcpyDeviceToDevice, stream);
  hipMemcpyAsync(h2b2[0], h1b2[p1], (size_t)NB*NH*2, hipMemcpyDeviceToDevice, stream);
  p2 = 0;

  // ---- pass 2: GRU2 ----
  if (cache_start > 0){
    hipMemsetAsync(h1f, 0, (size_t)NB*NH*4, stream);
    hipMemsetAsync(h1b2[0], 0, (size_t)NB*NH*2, stream);
    p1 = 0;
  }
  // prefix: recompute GRU1 inline, then GRU2 (both dual-A fused)
  for (int t = 0; t < cache_start; ++t){
    emb_kernel<<<emb_grid, blk, 0, stream>>>(obs, We, be, embb, t);
    fused_gru_step<<<fgrid, blk, 0, stream>>>(
        nullptr, embb, NE, wE1i, e1bih,
        h1b2[p1], wE1h, e1bhh, h1f, h1f, h1b2[p1^1], nullptr);
    p1 ^= 1;
    fused_gru_step<<<fgrid, blk, 0, stream>>>(
        nullptr, h1b2[p1], NH, wE2i, e2bih,
        h2b2[p2], wE2h, e2bhh, h2f, h2f, h2b2[p2^1], nullptr);
    p2 ^= 1;
    if (t == NT - 2)
      outproj_kernel<<<dim3(NB), blk, 0, stream>>>(h2f, Wout, bout, last, nullptr, 0);
  }
  // cached region: bulk gx2 from cache, fused steps
  for (int t0 = cache_start; t0 < NT; t0 += C){
    int Ce = (NT - t0 < C) ? NT - t0 : C;
    gemm_big_kernel<<<dim3(NG/128, Ce*8), blk, 0, stream>>>(
        cache + (size_t)(t0 - cache_start)*NB*NH, NH, wE2i, e2bih, gxbuf);
    for (int tc = 0; tc < Ce; ++tc){
      int t = t0 + tc;
      fused_gru_step<<<fgrid, blk, 0, stream>>>(
          gxbuf + (size_t)tc*NB*NG, nullptr, 0, nullptr, nullptr,
          h2b2[p2], wE2h, e2bhh, h2f, h2f, h2b2[p2^1], nullptr);
      p2 ^= 1;
      if (t == NT - 2)
        outproj_kernel<<<dim3(NB), blk, 0, stream>>>(h2f, Wout, bout, last, nullptr, 0);
    }
  }

  // ---- decoder: demb + fused1 + fused2 + outproj per step ----
  const int c2 = p2;    // current h2 plane (stays fixed: f2 rewrites it each step)
  for (int t = 0; t < NPRED; ++t){
    demb_kernel<<<emb_grid, blk, 0, stream>>>(last, Wed, bed, embb);
    fused_gru_step<<<fgrid, blk, 0, stream>>>(
        nullptr, embb, NE, wD1i, d1bih,
        h2b2[c2], wD1h, d1bhh, h2f, h1f, h1b2[0], nullptr);
    fused_gru_step<<<fgrid, blk, 0, stream>>>(
        nullptr, h1b2[0], NH, wD2i, d2bih,
        h1b2[0], wD2h, d2bhh, h1f, h2f, h2b2[c2], nullptr);
    outproj_kernel<<<dim3(NB), blk, 0, stream>>>(h2f, Wout, bout, last, out, t);
  }
}

// Round 5
// 8357.233 us; speedup vs baseline: 1.6779x; 1.6779x over previous
//
#include <hip/hip_runtime.h>
#include <stdint.h>

#define NB 1024
#define NT 100
#define NPRED 30
#define NE 512
#define NH 1024
#define NG (3*NH)

typedef unsigned short u16;
typedef unsigned int u32;
typedef u16 u16x4 __attribute__((ext_vector_type(4)));
typedef float f32x4 __attribute__((ext_vector_type(4)));
typedef __bf16 bf16x8 __attribute__((ext_vector_type(8)));

__device__ __forceinline__ u16 f2b(float f){
  u32 u = __float_as_uint(f);
  u = (u + 0x7FFFu + ((u >> 16) & 1u)) >> 16;
  return (u16)u;
}
__device__ __forceinline__ float sig_(float x){ return 1.0f/(1.0f+__expf(-x)); }
__device__ __forceinline__ float tanh_(float x){
  float e = __expf(2.0f*fabsf(x));
  return copysignf(1.0f - 2.0f/(e+1.0f), x);
}

// ---------------- fp32 -> bf16 conversion ----------------
__global__ void cvt_kernel(const float* src, u16* dst, int n4){
  int i = blockIdx.x*256 + threadIdx.x;
  if (i < n4){
    f32x4 v = ((const f32x4*)src)[i];
    u16x4 o;
    o[0]=f2b(v[0]); o[1]=f2b(v[1]); o[2]=f2b(v[2]); o[3]=f2b(v[3]);
    ((u16x4*)dst)[i] = o;
  }
}

// ---------------- per-step input embedding (K=2, trivial) ----------------
__global__ void emb_kernel(const float* __restrict__ obs, const float* __restrict__ We,
                           const float* __restrict__ be, u16* __restrict__ out, int t){
  int idx = blockIdx.x*256 + threadIdx.x;      // over NB*NE
  int b = idx >> 9, e = idx & 511;
  float x0 = obs[(b*NT + t)*2], x1 = obs[(b*NT + t)*2 + 1];
  out[idx] = f2b(tanh_(We[e*2]*x0 + We[e*2+1]*x1 + be[e]));
}

__global__ void demb_kernel(const float* __restrict__ last, const float* __restrict__ Wed,
                            const float* __restrict__ bed, u16* __restrict__ out){
  int idx = blockIdx.x*256 + threadIdx.x;      // over NB*NE
  int b = idx >> 9, e = idx & 511;
  out[idx] = f2b(tanh_(Wed[e*2]*last[b*2] + Wed[e*2+1]*last[b*2+1] + bed[e]));
}

// ---------------- async global->LDS (16B per lane) ----------------
__device__ __forceinline__ void gload16(const u16* g, const u16* lds){
  __builtin_amdgcn_global_load_lds(
      (const __attribute__((address_space(1))) void*)g,
      (__attribute__((address_space(3))) void*)lds, 16, 0, 0);
}

// ---------------- 128x128 bf16 GEMM tile, BK=64, dbuf LDS, XOR-swizzled ----------------
// LDS(row, chunk16B) holds global(row, chunk ^ (row&7)).
// Staging: linear LDS dest (global_load_lds requirement), per-lane pre-swizzled
// global source column. Reads: ds_read_b128 with chunk ^= (row&7) -> conflict-free
// (fr-lanes 0..7 span all 32 banks; 8..15 alias 2-way = free).
__device__ __forceinline__ void gemm_tile_body(
    const u16* __restrict__ A, int lda,
    const u16* __restrict__ W, int K,
    const float* __restrict__ bias, float* __restrict__ C,
    int bRow, int bCol)
{
  __shared__ __align__(16) u16 As[2][128][64];
  __shared__ __align__(16) u16 Bs[2][128][64];

  const int tid = threadIdx.x;
  const int w = tid >> 6, l = tid & 63;
  const int wm = w >> 1, wn = w & 1;           // 2x2 waves -> 64x64 per wave
  const int fr = l & 15, lhi = l >> 4;         // fragment row, k-group
  // staging: lane l -> LDS(row = slab*8 + (l>>3), chunk = l&7);
  // source global chunk = (l&7) ^ (l>>3)  [since row&7 == l>>3]
  const int srow = l >> 3;
  const int gcol = (((l & 7) ^ srow) * 8);     // u16 units

  f32x4 acc[4][4];
  #pragma unroll
  for (int m=0;m<4;m++)
    #pragma unroll
    for (int n=0;n<4;n++) acc[m][n] = (f32x4)0.0f;

  const u16* Ab = A + (size_t)bRow*lda + gcol;
  const u16* Wb = W + (size_t)bCol*K + gcol;
  const int NK = K >> 6;

  // prologue: stage buf 0 (wave w stages slabs 4w..4w+3; slab = 8 rows = 1KB)
  #pragma unroll
  for (int s4=0;s4<4;s4++){
    int slab = w*4 + s4;
    int row = slab*8 + srow;
    gload16(Ab + (size_t)row*lda, &As[0][slab*8][0]);
    gload16(Wb + (size_t)row*K,   &Bs[0][slab*8][0]);
  }
  __syncthreads();

  for (int t = 0; t < NK; ++t){
    const int cur = t & 1;
    if (t + 1 < NK){
      const int k0 = (t+1)*64;
      #pragma unroll
      for (int s4=0;s4<4;s4++){
        int slab = w*4 + s4;
        int row = slab*8 + srow;
        gload16(Ab + (size_t)row*lda + k0, &As[cur^1][slab*8][0]);
        gload16(Wb + (size_t)row*K   + k0, &Bs[cur^1][slab*8][0]);
      }
    }
    const u16* Ac = &As[cur][0][0];
    const u16* Bc = &Bs[cur][0][0];
    #pragma unroll
    for (int kk=0; kk<2; ++kk){
      const int ch = (((kk*4 + lhi) ^ (l & 7)) * 8);   // swizzled 16B chunk
      bf16x8 af[4], bfr[4];
      #pragma unroll
      for (int m=0;m<4;m++)
        af[m] = *(const bf16x8*)(Ac + (size_t)(wm*64 + m*16 + fr)*64 + ch);
      #pragma unroll
      for (int n=0;n<4;n++)
        bfr[n] = *(const bf16x8*)(Bc + (size_t)(wn*64 + n*16 + fr)*64 + ch);
      #pragma unroll
      for (int m=0;m<4;m++)
        #pragma unroll
        for (int n=0;n<4;n++)
          acc[m][n] = __builtin_amdgcn_mfma_f32_16x16x32_bf16(af[m], bfr[n], acc[m][n], 0, 0, 0);
    }
    __syncthreads();
  }

  // epilogue: C/D layout col = lane&15, row = (lane>>4)*4 + reg  [m89/m91 verified]
  const int crow = lhi * 4, ccol = l & 15;
  #pragma unroll
  for (int n=0;n<4;n++){
    int col = bCol + wn*64 + n*16 + ccol;
    float bv = bias[col];
    #pragma unroll
    for (int m=0;m<4;m++){
      int row = bRow + wm*64 + m*16 + crow;
      float* Cp = C + (size_t)row*NG + col;
      #pragma unroll
      for (int r=0;r<4;r++) Cp[(size_t)r*NG] = acc[m][n][r] + bv;
    }
  }
}

// two independent GEMMs in one launch: z=0 (gx), z=1 (gh)
__global__ __launch_bounds__(256)
void gemm_dual_kernel(
  const u16* A0, int lda0, int K0, const u16* W0, const float* bias0, float* C0,
  const u16* A1, int lda1, int K1, const u16* W1, const float* bias1, float* C1)
{
  if (blockIdx.z == 0)
    gemm_tile_body(A0, lda0, W0, K0, bias0, C0, blockIdx.y*128, blockIdx.x*128);
  else
    gemm_tile_body(A1, lda1, W1, K1, bias1, C1, blockIdx.y*128, blockIdx.x*128);
}

// ---------------- GRU cell (memory-bound) ----------------
__global__ void gru_cell_kernel(const float* __restrict__ gx, const float* __restrict__ gh,
                                const float* __restrict__ hin, float* __restrict__ hout,
                                u16* __restrict__ houtb, u16* __restrict__ seq)
{
  int idx = blockIdx.x*256 + threadIdx.x;   // over NB*NH/4
  int b = idx >> 8, jq = idx & 255;         // NH/4 = 256
  int base = b*768;                         // 3H/4
  const f32x4* gx4 = (const f32x4*)gx;
  const f32x4* gh4 = (const f32x4*)gh;
  f32x4 xr = gx4[base + jq], xz = gx4[base + 256 + jq], xn = gx4[base + 512 + jq];
  f32x4 hr = gh4[base + jq], hz = gh4[base + 256 + jq], hn = gh4[base + 512 + jq];
  f32x4 hv = ((const f32x4*)hin)[idx];
  f32x4 o; u16x4 ob;
  #pragma unroll
  for (int c=0;c<4;c++){
    float r = sig_(xr[c] + hr[c]);
    float z = sig_(xz[c] + hz[c]);
    float n = tanh_(xn[c] + r*hn[c]);
    float h = (1.0f - z)*n + z*hv[c];
    o[c] = h; ob[c] = f2b(h);
  }
  ((f32x4*)hout)[idx] = o;
  ((u16x4*)houtb)[idx] = ob;
  if (seq) ((u16x4*)seq)[idx] = ob;
}

// ---------------- output projection: (B,H) @ Wout^T (2,H) + bout ----------------
__global__ void outproj_kernel(const float* __restrict__ h, const float* __restrict__ Wout,
                               const float* __restrict__ bout, float* __restrict__ last,
                               float* __restrict__ dout, int t)
{
  int b = blockIdx.x, tid = threadIdx.x;
  float s0 = 0.f, s1 = 0.f;
  const float* hb_ = h + (size_t)b*NH;
  for (int j = tid; j < NH; j += 256){
    float hv = hb_[j];
    s0 += hv * Wout[j];
    s1 += hv * Wout[NH + j];
  }
  #pragma unroll
  for (int off = 32; off > 0; off >>= 1){
    s0 += __shfl_down(s0, off);
    s1 += __shfl_down(s1, off);
  }
  __shared__ float red[8];
  int w = tid >> 6;
  if ((tid & 63) == 0){ red[w*2] = s0; red[w*2+1] = s1; }
  __syncthreads();
  if (tid == 0){
    float o0 = red[0]+red[2]+red[4]+red[6] + bout[0];
    float o1 = red[1]+red[3]+red[5]+red[7] + bout[1];
    last[b*2]   = o0;
    last[b*2+1] = o1;
    if (dout){ dout[(size_t)b*(NPRED*2) + t*2]     = o0;
               dout[(size_t)b*(NPRED*2) + t*2 + 1] = o1; }
  }
}

extern "C" void kernel_launch(void* const* d_in, const int* in_sizes, int n_in,
                              void* d_out, int out_size, void* d_ws, size_t ws_size,
                              hipStream_t stream)
{
  (void)in_sizes; (void)n_in; (void)out_size;
  const float* obs  = (const float*)d_in[0];
  const float* We   = (const float*)d_in[1];
  const float* be   = (const float*)d_in[2];
  const float* Wed  = (const float*)d_in[3];
  const float* bed  = (const float*)d_in[4];
  const float* e1Wih = (const float*)d_in[5];
  const float* e1Whh = (const float*)d_in[6];
  const float* e1bih = (const float*)d_in[7];
  const float* e1bhh = (const float*)d_in[8];
  const float* e2Wih = (const float*)d_in[9];
  const float* e2Whh = (const float*)d_in[10];
  const float* e2bih = (const float*)d_in[11];
  const float* e2bhh = (const float*)d_in[12];
  const float* d1Wih = (const float*)d_in[13];
  const float* d1Whh = (const float*)d_in[14];
  const float* d1bih = (const float*)d_in[15];
  const float* d1bhh = (const float*)d_in[16];
  const float* d2Wih = (const float*)d_in[17];
  const float* d2Whh = (const float*)d_in[18];
  const float* d2bih = (const float*)d_in[19];
  const float* d2bhh = (const float*)d_in[20];
  const float* Wout = (const float*)d_in[21];
  const float* bout = (const float*)d_in[22];
  float* out = (float*)d_out;

  // ---- ws-adaptive workspace layout (round-2 proven) ----
  char* ws = (char*)d_ws;
  size_t off = 0;
  auto alloc = [&](size_t bytes)->char* {
    char* p = ws + off;
    off += (bytes + 255) & ~(size_t)255;
    return p;
  };
  u16* wE1i = (u16*)alloc((size_t)NG*NE*2);
  u16* wE1h = (u16*)alloc((size_t)NG*NH*2);
  u16* wE2i = (u16*)alloc((size_t)NG*NH*2);
  u16* wE2h = (u16*)alloc((size_t)NG*NH*2);
  u16* wD1i = (u16*)alloc((size_t)NG*NE*2);
  u16* wD1h = (u16*)alloc((size_t)NG*NH*2);
  u16* wD2i = (u16*)alloc((size_t)NG*NH*2);
  u16* wD2h = (u16*)alloc((size_t)NG*NH*2);
  u16* embb  = (u16*)alloc((size_t)NB*NE*2);
  float* h1f = (float*)alloc((size_t)NB*NH*4);
  u16*   h1b = (u16*)alloc((size_t)NB*NH*2);
  float* h2f = (float*)alloc((size_t)NB*NH*4);
  u16*   h2b = (u16*)alloc((size_t)NB*NH*2);
  float* gx  = (float*)alloc((size_t)NB*NG*4);
  float* gh  = (float*)alloc((size_t)NB*NG*4);
  float* last = (float*)alloc((size_t)NB*2*4);

  // enc1 cache: as many TRAILING steps as fit; prefix recomputed in pass 2.
  const size_t slot = (size_t)NB*NH*2;     // 2 MB/step
  size_t avail = (ws_size > off + (1u<<20)) ? (ws_size - off - (1u<<20)) : 0;
  int cs = (int)(avail / slot);
  if (cs > NT) cs = NT;
  u16* cache = (u16*)alloc((size_t)cs * slot);
  const int cache_start = NT - cs;

  // ---- init ----
  hipMemsetAsync(h1f, 0, (size_t)NB*NH*4, stream);
  hipMemsetAsync(h1b, 0, (size_t)NB*NH*2, stream);

  auto cvt = [&](const float* src, u16* dst, size_t n){
    int n4 = (int)(n >> 2);
    cvt_kernel<<<dim3((n4 + 255)/256), dim3(256), 0, stream>>>(src, dst, n4);
  };
  cvt(e1Wih, wE1i, (size_t)NG*NE);
  cvt(e1Whh, wE1h, (size_t)NG*NH);
  cvt(e2Wih, wE2i, (size_t)NG*NH);
  cvt(e2Whh, wE2h, (size_t)NG*NH);
  cvt(d1Wih, wD1i, (size_t)NG*NE);
  cvt(d1Whh, wD1h, (size_t)NG*NH);
  cvt(d2Wih, wD2i, (size_t)NG*NH);
  cvt(d2Whh, wD2h, (size_t)NG*NH);

  const dim3 blk(256);
  const dim3 dual_grid(NG/128, NB/128, 2);   // 24 x 8 x 2 = 384 blocks
  const dim3 emb_grid((NB*NE)/256);          // 2048
  const dim3 cell_grid((NB*NH/4)/256);       // 1024

  // ---- pass 1: GRU1 over all T (stores trailing cs outputs) ----
  for (int t = 0; t < NT; ++t){
    emb_kernel<<<emb_grid, blk, 0, stream>>>(obs, We, be, embb, t);
    gemm_dual_kernel<<<dual_grid, blk, 0, stream>>>(
        embb, NE, NE, wE1i, e1bih, gx,
        h1b,  NH, NH, wE1h, e1bhh, gh);
    u16* slot_p = (t >= cache_start) ? cache + (size_t)(t - cache_start)*NB*NH : (u16*)nullptr;
    gru_cell_kernel<<<cell_grid, blk, 0, stream>>>(gx, gh, h1f, h1f, h1b, slot_p);
  }

  // GRU2 initial hidden = GRU1 final hidden (the reference quirk)
  hipMemcpyAsync(h2f, h1f, (size_t)NB*NH*4, hipMemcpyDeviceToDevice, stream);
  hipMemcpyAsync(h2b, h1b, (size_t)NB*NH*2, hipMemcpyDeviceToDevice, stream);

  // ---- pass 2: GRU2 over all T; recompute GRU1 prefix where not cached ----
  if (cache_start > 0){
    hipMemsetAsync(h1f, 0, (size_t)NB*NH*4, stream);
    hipMemsetAsync(h1b, 0, (size_t)NB*NH*2, stream);
  }
  for (int t = 0; t < cache_start; ++t){
    emb_kernel<<<emb_grid, blk, 0, stream>>>(obs, We, be, embb, t);
    gemm_dual_kernel<<<dual_grid, blk, 0, stream>>>(
        embb, NE, NE, wE1i, e1bih, gx,
        h1b,  NH, NH, wE1h, e1bhh, gh);
    gru_cell_kernel<<<cell_grid, blk, 0, stream>>>(gx, gh, h1f, h1f, h1b, (u16*)nullptr);
    gemm_dual_kernel<<<dual_grid, blk, 0, stream>>>(
        h1b, NH, NH, wE2i, e2bih, gx,
        h2b, NH, NH, wE2h, e2bhh, gh);
    gru_cell_kernel<<<cell_grid, blk, 0, stream>>>(gx, gh, h2f, h2f, h2b, (u16*)nullptr);
    if (t == NT - 2)
      outproj_kernel<<<dim3(NB), blk, 0, stream>>>(h2f, Wout, bout, last, (float*)nullptr, 0);
  }
  for (int t = cache_start; t < NT; ++t){
    const u16* enc1_t = cache + (size_t)(t - cache_start)*NB*NH;
    gemm_dual_kernel<<<dual_grid, blk, 0, stream>>>(
        enc1_t, NH, NH, wE2i, e2bih, gx,
        h2b,    NH, NH, wE2h, e2bhh, gh);
    gru_cell_kernel<<<cell_grid, blk, 0, stream>>>(gx, gh, h2f, h2f, h2b, (u16*)nullptr);
    if (t == NT - 2)
      outproj_kernel<<<dim3(NB), blk, 0, stream>>>(h2f, Wout, bout, last, (float*)nullptr, 0);
  }

  // ---- autoregressive decoder (carry = h2, intermediate = h1) ----
  for (int t = 0; t < NPRED; ++t){
    demb_kernel<<<emb_grid, blk, 0, stream>>>(last, Wed, bed, embb);
    gemm_dual_kernel<<<dual_grid, blk, 0, stream>>>(
        embb, NE, NE, wD1i, d1bih, gx,
        h2b,  NH, NH, wD1h, d1bhh, gh);
    gru_cell_kernel<<<cell_grid, blk, 0, stream>>>(gx, gh, h2f, h1f, h1b, (u16*)nullptr);
    gemm_dual_kernel<<<dual_grid, blk, 0, stream>>>(
        h1b, NH, NH, wD2i, d2bih, gx,
        h1b, NH, NH, wD2h, d2bhh, gh);
    gru_cell_kernel<<<cell_grid, blk, 0, stream>>>(gx, gh, h1f, h2f, h2b, (u16*)nullptr);
    outproj_kernel<<<dim3(NB), blk, 0, stream>>>(h2f, Wout, bout, last, out, t);
  }
}